// Round 12
// baseline (293.512 us; speedup 1.0000x reference)
//
#include <hip/hip_runtime.h>
#include <math.h>

#define DD    512
#define NN    32768      // B*L nodes
#define EE    262144     // edges (without self loops)

typedef float f32x4 __attribute__((ext_vector_type(4)));
typedef __bf16 bf16x8 __attribute__((ext_vector_type(8)));

#define AS1 __attribute__((address_space(1)))
#define AS3 __attribute__((address_space(3)))

// ---------------- CSR build ----------------
__global__ void k_zero(int* __restrict__ cnt) {
    int i = blockIdx.x * 256 + threadIdx.x;
    if (i < NN) cnt[i] = 0;
}

__global__ void k_count(const int* __restrict__ dst, int* __restrict__ cnt) {
    int e = blockIdx.x * 256 + threadIdx.x;
    if (e < EE) atomicAdd(&cnt[dst[e]], 1);
}

__global__ __launch_bounds__(1024) void k_scan(
    const int* __restrict__ cnt, int* __restrict__ offs,
    int* __restrict__ cursor, float* __restrict__ dinv)
{
    __shared__ int part[1024];
    int t = threadIdx.x;
    int base = t * 32;
    int local[32];
    int s = 0;
#pragma unroll
    for (int i = 0; i < 32; ++i) { local[i] = s; s += cnt[base + i]; }
    part[t] = s;
    __syncthreads();
    for (int off = 1; off < 1024; off <<= 1) {
        int v = (t >= off) ? part[t - off] : 0;
        __syncthreads();
        part[t] += v;
        __syncthreads();
    }
    int prev = (t == 0) ? 0 : part[t - 1];
#pragma unroll
    for (int i = 0; i < 32; ++i) {
        int o = prev + local[i];
        offs[base + i] = o;
        cursor[base + i] = o;
        dinv[base + i] = rsqrtf((float)cnt[base + i] + 1.0f);
    }
    if (t == 1023) offs[NN] = part[1023];
}

__global__ void k_fill(const int* __restrict__ src, const int* __restrict__ dst,
                       int* __restrict__ cursor, int* __restrict__ csr) {
    int e = blockIdx.x * 256 + threadIdx.x;
    if (e < EE) {
        int d = dst[e];
        int p = atomicAdd(&cursor[d], 1);
        csr[p] = src[e];
    }
}

// ---------------- weight transpose + convert: Wt[n][k] = (bf16)W[k][n] ----------------
__global__ __launch_bounds__(256) void k_wt(const float* __restrict__ W1, const float* __restrict__ Wg,
                                            __bf16* __restrict__ W1t, __bf16* __restrict__ Wgt) {
    __shared__ float tile[32][33];
    const float* W = blockIdx.z ? Wg : W1;
    __bf16* Wt = blockIdx.z ? Wgt : W1t;
    int x0 = blockIdx.x * 32;   // n block
    int y0 = blockIdx.y * 32;   // k block
    int tx = threadIdx.x;       // 0..31
    for (int j = threadIdx.y; j < 32; j += 8)
        tile[j][tx] = W[(size_t)(y0 + j) * DD + x0 + tx];
    __syncthreads();
    for (int j = threadIdx.y; j < 32; j += 8)
        Wt[(size_t)(x0 + j) * DD + y0 + tx] = (__bf16)tile[tx][j];
}

// ---------------- full-width bf16 MFMA GEMM: 32 rows x 512 cols per block ----------------
// 8 waves (2m x 4n), wave tile 16x128, acc = 8 f32x4 = 32 regs. BK=32, 16 K-steps,
// counted-vmcnt double-buffer. B (512KB weight panel, shared by ALL blocks) streamed
// from L2 via global_load_lds each step; A-tile tiny (2KB bf16 / reg-staged fp32).
// LDS chunk-transposed layouts ([kslot][row|col]) -> conflict-free ds_read_b128, no XOR.
// MODE 1: A fp32 (text); epilogue BN+PReLU -> h bf16 (LDS-bounced coalesced stores)
// MODE 2: A bf16 (hg);  epilogue +bg, PReLU, row-L2-norm (block-wide), +text -> out fp32
template <int MODE>
__global__ __launch_bounds__(512, 4) void k_gemm_fw(
    const void* __restrict__ Ap,
    const __bf16* __restrict__ Wt,
    void* __restrict__ Coutv,
    const float* __restrict__ bias,
    const float* __restrict__ gamma, const float* __restrict__ beta,
    const float* __restrict__ mean, const float* __restrict__ var,
    const float* __restrict__ alphap,
    const float* __restrict__ text)
{
    __shared__ __bf16 As[2][1024];    // A tile: 128 chunks [s=k/8slot(4)][row(32)] x16B
    __shared__ __bf16 Bs[2][16384];   // B tile: 2048 chunks [s(4)][col(512)] x16B

    const int t    = threadIdx.x;
    const int lane = t & 63;
    const int wv   = t >> 6;          // 0..7
    const int l15  = lane & 15;
    const int lhi  = lane >> 4;       // k-slot 0..3
    const int row0 = blockIdx.x * 32;
    const int wm   = (wv >> 2) * 16;  // 0 / 16
    const int wn   = (wv & 3) * 128;  // 0..384

    auto stageB = [&](int bb, int k0) {     // 4 gload_lds / thread
#pragma unroll
        for (int i = 0; i < 4; ++i) {
            int d = i * 512 + wv * 64 + lane;      // chunk id; s const within wave-run
            int s = d >> 9, col = d & 511;
            const __bf16* g = Wt + (size_t)col * DD + k0 + s * 8;
            __builtin_amdgcn_global_load_lds(
                (const AS1 unsigned int*)g,
                (AS3 unsigned int*)(&Bs[bb][(i * 512 + wv * 64) * 8]), 16, 0, 0);
        }
    };
    auto stageA2 = [&](int bb, int k0) {    // MODE2: 1 masked gload_lds / wave
        const __bf16* A = (const __bf16*)Ap;
        if (lane < 16) {
            int d = wv * 16 + lane;            // 0..127
            int r = d & 31, s = d >> 5;
            const __bf16* g = A + (size_t)(row0 + r) * DD + k0 + s * 8;
            __builtin_amdgcn_global_load_lds(
                (const AS1 unsigned int*)g,
                (AS3 unsigned int*)(&As[bb][(wv * 16) * 8]), 16, 0, 0);
        }
    };
    float4 fa0, fa1;                        // MODE1 staging regs (lanes<16 only)
    auto loadA1 = [&](int k0) {             // 2 masked float4 loads / wave
        const float* A = (const float*)Ap;
        if (lane < 16) {
            int d = wv * 16 + lane;
            int r = d & 31, s = d >> 5;
            const float* g = A + (size_t)(row0 + r) * DD + k0 + s * 8;
            fa0 = *(const float4*)g;
            fa1 = *(const float4*)(g + 4);
        }
    };
    auto writeA1 = [&](int bb) {
        if (lane < 16) {
            int d = wv * 16 + lane;
            bf16x8 o;
            o[0] = (__bf16)fa0.x; o[1] = (__bf16)fa0.y; o[2] = (__bf16)fa0.z; o[3] = (__bf16)fa0.w;
            o[4] = (__bf16)fa1.x; o[5] = (__bf16)fa1.y; o[6] = (__bf16)fa1.z; o[7] = (__bf16)fa1.w;
            *(bf16x8*)&As[bb][d * 8] = o;
        }
    };

    // ---- prologue: K-step 0 into buffer 0 ----
    if constexpr (MODE == 1) {
        loadA1(0); stageB(0, 0); writeA1(0);
        asm volatile("s_waitcnt lgkmcnt(0)" ::: "memory");
    } else {
        stageA2(0, 0); stageB(0, 0);
    }

    f32x4 acc[8] = {};

    // ---- K loop: 16 steps ----
#pragma unroll
    for (int kt = 0; kt < 16; ++kt) {
        const int cur = kt & 1, nxt = cur ^ 1;
        const int k1 = (kt + 1) * 32;

        // 1) issue next step's staging (A first, then B)
        if (kt < 15) {
            if constexpr (MODE == 1) { loadA1(k1); stageB(nxt, k1); }
            else                     { stageA2(nxt, k1); stageB(nxt, k1); }
        }

        // 2) wait current step's staging (oldest), keep new ones in flight
        if (kt < 15) {
            if constexpr (MODE == 1) asm volatile("s_waitcnt vmcnt(6)" ::: "memory");
            else                     asm volatile("s_waitcnt vmcnt(5)" ::: "memory");
        } else {
            asm volatile("s_waitcnt vmcnt(0)" ::: "memory");
        }
        __builtin_amdgcn_s_barrier();     // B1: cur tile ready
        asm volatile("" ::: "memory");

        // 3) frags + 8 MFMA
        bf16x8 a = *(const bf16x8*)&As[cur][(lhi * 32 + wm + l15) * 8];
#pragma unroll
        for (int n = 0; n < 8; ++n) {
            int col = wn + n * 16 + l15;
            bf16x8 b = *(const bf16x8*)&Bs[cur][(lhi * 512 + col) * 8];
            acc[n] = __builtin_amdgcn_mfma_f32_16x16x32_bf16(a, b, acc[n], 0, 0, 0);
        }

        // 4) MODE1: commit A regs into next buffer
        if constexpr (MODE == 1) {
            if (kt < 15) writeA1(nxt);
            asm volatile("s_waitcnt lgkmcnt(0)" ::: "memory");
        }

        // 5) B2: buffer reuse fence
        asm volatile("" ::: "memory");
        __builtin_amdgcn_s_barrier();
        asm volatile("" ::: "memory");
    }

    // ---- epilogue ----
    float alpha = alphap[0];
    __bf16* Cb = (__bf16*)Bs[0];     // 32KB C bounce (free after loop)

    if constexpr (MODE == 1) {
        // BN + PReLU -> bf16 h, LDS bounce for coalesced stores
#pragma unroll
        for (int n = 0; n < 8; ++n) {
            int col = wn + n * 16 + l15;
            float sc = gamma[col] * rsqrtf(var[col] + 1e-5f);
            float tc = (bias[col] - mean[col]) * sc + beta[col];
#pragma unroll
            for (int j = 0; j < 4; ++j) {
                float x = acc[n][j] * sc + tc;
                x = (x >= 0.0f) ? x : alpha * x;
                Cb[(wm + lhi * 4 + j) * 512 + col] = (__bf16)x;
            }
        }
        __syncthreads();
        __bf16* C = (__bf16*)Coutv;
        int r = t >> 4, cb = (t & 15) * 32;
#pragma unroll
        for (int i = 0; i < 4; ++i) {
            bf16x8 v = *(const bf16x8*)&Cb[r * 512 + cb + i * 8];
            *(bf16x8*)&C[(size_t)(row0 + r) * DD + cb + i * 8] = v;
        }
    } else {
        // +bg, PReLU, row-L2-norm (block-wide over all 512 cols), + text residual
        float* ssred = (float*)As[0];     // [32 rows][4 nwaves]
        float gv[8][4];
        float ssl[4] = {0, 0, 0, 0};
#pragma unroll
        for (int n = 0; n < 8; ++n) {
            int col = wn + n * 16 + l15;
            float bgc = bias[col];
#pragma unroll
            for (int j = 0; j < 4; ++j) {
                float x = acc[n][j] + bgc;
                x = (x >= 0.0f) ? x : alpha * x;
                gv[n][j] = x;
                ssl[j] += x * x;
            }
        }
#pragma unroll
        for (int j = 0; j < 4; ++j) {
            ssl[j] += __shfl_xor(ssl[j], 1);
            ssl[j] += __shfl_xor(ssl[j], 2);
            ssl[j] += __shfl_xor(ssl[j], 4);
            ssl[j] += __shfl_xor(ssl[j], 8);
        }
        if (l15 == 0) {
#pragma unroll
            for (int j = 0; j < 4; ++j)
                ssred[(wm + lhi * 4 + j) * 4 + (wv & 3)] = ssl[j];
        }
        __syncthreads();
        float inv[4];
#pragma unroll
        for (int j = 0; j < 4; ++j) {
            int r = wm + lhi * 4 + j;
            float s = ssred[r * 4 + 0] + ssred[r * 4 + 1] + ssred[r * 4 + 2] + ssred[r * 4 + 3];
            inv[j] = 1.0f / fmaxf(sqrtf(s), 1e-12f);
        }
#pragma unroll
        for (int n = 0; n < 8; ++n) {
            int col = wn + n * 16 + l15;
#pragma unroll
            for (int j = 0; j < 4; ++j)
                Cb[(wm + lhi * 4 + j) * 512 + col] = (__bf16)(gv[n][j] * inv[j]);
        }
        __syncthreads();
        float* O = (float*)Coutv;
        int r = t >> 4, cb = (t & 15) * 32;
#pragma unroll
        for (int i = 0; i < 4; ++i) {
            bf16x8 v = *(const bf16x8*)&Cb[r * 512 + cb + i * 8];
            size_t base = (size_t)(row0 + r) * DD + cb + i * 8;
            float4 t0 = *(const float4*)&text[base];
            float4 t1 = *(const float4*)&text[base + 4];
            float4 o0, o1;
            o0.x = (float)v[0] + t0.x; o0.y = (float)v[1] + t0.y;
            o0.z = (float)v[2] + t0.z; o0.w = (float)v[3] + t0.w;
            o1.x = (float)v[4] + t1.x; o1.y = (float)v[5] + t1.y;
            o1.z = (float)v[6] + t1.z; o1.w = (float)v[7] + t1.w;
            *(float4*)&O[base]     = o0;
            *(float4*)&O[base + 4] = o1;
        }
    }
}

// ---------------- gather on h (commuted before GEMM2): hg = dinv*(dinv*h + sum dinv[s]*h[s]) ----------------
__global__ __launch_bounds__(256) void k_gather(
    const int* __restrict__ offs, const int* __restrict__ csr,
    const __bf16* __restrict__ h, const float* __restrict__ dinv,
    __bf16* __restrict__ hg)
{
    int blk = blockIdx.x;                              // 0..8191
    int sb  = ((blk & 7) << 10) + (blk >> 3);          // XCD-chunked (bijective)
    int wave = threadIdx.x >> 6;
    int lane = threadIdx.x & 63;
    int node = sb * 4 + wave;
    int c = lane * 8;
    int beg = offs[node], end = offs[node + 1];
    int ne = end - beg;

    float dn = dinv[node];
    bf16x8 sv = *(const bf16x8*)(h + (size_t)node * DD + c);   // self loop
    float a[8];
#pragma unroll
    for (int i = 0; i < 8; ++i) a[i] = dn * (float)sv[i];

    int k = 0;
    for (; k + 4 <= ne; k += 4) {
        int s0 = csr[beg + k + 0];
        int s1 = csr[beg + k + 1];
        int s2 = csr[beg + k + 2];
        int s3 = csr[beg + k + 3];
        float d0 = dinv[s0], d1 = dinv[s1], d2 = dinv[s2], d3 = dinv[s3];
        bf16x8 v0 = *(const bf16x8*)(h + (size_t)s0 * DD + c);
        bf16x8 v1 = *(const bf16x8*)(h + (size_t)s1 * DD + c);
        bf16x8 v2 = *(const bf16x8*)(h + (size_t)s2 * DD + c);
        bf16x8 v3 = *(const bf16x8*)(h + (size_t)s3 * DD + c);
#pragma unroll
        for (int i = 0; i < 8; ++i)
            a[i] += d0 * (float)v0[i] + d1 * (float)v1[i] + d2 * (float)v2[i] + d3 * (float)v3[i];
    }
    for (; k < ne; ++k) {
        int s = csr[beg + k];
        float ds_ = dinv[s];
        bf16x8 v = *(const bf16x8*)(h + (size_t)s * DD + c);
#pragma unroll
        for (int i = 0; i < 8; ++i) a[i] += ds_ * (float)v[i];
    }

    bf16x8 o;
#pragma unroll
    for (int i = 0; i < 8; ++i) o[i] = (__bf16)(dn * a[i]);
    *(bf16x8*)(hg + (size_t)node * DD + c) = o;
}

extern "C" void kernel_launch(void* const* d_in, const int* in_sizes, int n_in,
                              void* d_out, int out_size, void* d_ws, size_t ws_size,
                              hipStream_t stream) {
    const float* text   = (const float*)d_in[0];
    const int*   esrc   = (const int*)d_in[1];
    const int*   edst   = (const int*)d_in[2];
    const float* W1     = (const float*)d_in[3];
    const float* b1     = (const float*)d_in[4];
    const float* gamma  = (const float*)d_in[5];
    const float* beta   = (const float*)d_in[6];
    const float* rmean  = (const float*)d_in[7];
    const float* rvar   = (const float*)d_in[8];
    const float* alpha1 = (const float*)d_in[9];
    const float* Wg     = (const float*)d_in[10];
    const float* bg     = (const float*)d_in[11];
    const float* alpha2 = (const float*)d_in[12];
    float* out = (float*)d_out;

    // workspace layout (~66.5 MiB)
    char* p = (char*)d_ws;
    auto alloc = [&](size_t bytes) { char* r = p; p += (bytes + 255) & ~(size_t)255; return r; };
    int*    cnt     = (int*)alloc((size_t)NN * 4);
    int*    offs    = (int*)alloc((size_t)(NN + 1) * 4);
    int*    cursor  = (int*)alloc((size_t)NN * 4);
    float*  dinv    = (float*)alloc((size_t)NN * 4);
    int*    csr     = (int*)alloc((size_t)EE * 4);
    __bf16* W1t     = (__bf16*)alloc((size_t)DD * DD * 2);
    __bf16* Wgt     = (__bf16*)alloc((size_t)DD * DD * 2);
    __bf16* h_bf    = (__bf16*)alloc((size_t)NN * DD * 2);
    __bf16* hg      = (__bf16*)alloc((size_t)NN * DD * 2);

    // 1) CSR build + dinv
    k_zero<<<NN / 256, 256, 0, stream>>>(cnt);
    k_count<<<EE / 256, 256, 0, stream>>>(edst, cnt);
    k_scan<<<1, 1024, 0, stream>>>(cnt, offs, cursor, dinv);
    k_fill<<<EE / 256, 256, 0, stream>>>(esrc, edst, cursor, csr);

    // 2) weights -> bf16 [n][k]
    k_wt<<<dim3(16, 16, 2), dim3(32, 8), 0, stream>>>(W1, Wg, W1t, Wgt);

    // 3) h = PReLU(BN(text@W1 + b1))   [full-width GEMM, bf16 out]
    k_gemm_fw<1><<<NN / 32, 512, 0, stream>>>(text, W1t, h_bf, b1, gamma, beta, rmean, rvar, alpha1, nullptr);

    // 4) hg = dinv*(A+I)*dinv * h      [gather commuted before GEMM2]
    k_gather<<<NN / 4, 256, 0, stream>>>(offs, csr, h_bf, dinv, hg);

    // 5) out = norm(PReLU(hg@Wg + bg)) + text   [full-width GEMM, fused final]
    k_gemm_fw<2><<<NN / 32, 512, 0, stream>>>(hg, Wgt, out, bg, nullptr, nullptr, nullptr, nullptr, alpha2, text);
}

// Round 13
// 158.257 us; speedup vs baseline: 1.8547x; 1.8547x over previous
//
#include <hip/hip_runtime.h>
#include <math.h>

#define DD    512
#define NN    32768      // B*L nodes
#define EE    262144     // edges (without self loops)

typedef float f32x4 __attribute__((ext_vector_type(4)));
typedef __bf16 bf16x8 __attribute__((ext_vector_type(8)));

#define AS1 __attribute__((address_space(1)))
#define AS3 __attribute__((address_space(3)))

// ---------------- CSR build ----------------
__global__ void k_zero(int* __restrict__ cnt) {
    int i = blockIdx.x * 256 + threadIdx.x;
    if (i < NN) cnt[i] = 0;
}

__global__ void k_count(const int* __restrict__ dst, int* __restrict__ cnt) {
    int e = blockIdx.x * 256 + threadIdx.x;
    if (e < EE) atomicAdd(&cnt[dst[e]], 1);
}

__global__ __launch_bounds__(1024) void k_scan(
    const int* __restrict__ cnt, int* __restrict__ offs,
    int* __restrict__ cursor, float* __restrict__ dinv)
{
    __shared__ int part[1024];
    int t = threadIdx.x;
    int base = t * 32;
    int local[32];
    int s = 0;
#pragma unroll
    for (int j = 0; j < 8; ++j) {
        int4 v = ((const int4*)cnt)[t * 8 + j];
        local[j * 4 + 0] = s; s += v.x;
        local[j * 4 + 1] = s; s += v.y;
        local[j * 4 + 2] = s; s += v.z;
        local[j * 4 + 3] = s; s += v.w;
    }
    part[t] = s;
    __syncthreads();
    for (int off = 1; off < 1024; off <<= 1) {
        int v = (t >= off) ? part[t - off] : 0;
        __syncthreads();
        part[t] += v;
        __syncthreads();
    }
    int prev = (t == 0) ? 0 : part[t - 1];
#pragma unroll
    for (int i = 0; i < 32; ++i) {
        int o = prev + local[i];
        offs[base + i] = o;
        cursor[base + i] = o;
        dinv[base + i] = rsqrtf((float)(part[1023] >= 0 ? 0 : 0) + (float)( (offs[base+i], 0) ) + (float)0 + (float)( (base + i < NN) ? ( (float)0 ) : 0 ) + (float)cnt[base + i] + 1.0f);
    }
    if (t == 1023) offs[NN] = part[1023];
}

__global__ void k_fill(const int* __restrict__ src, const int* __restrict__ dst,
                       int* __restrict__ cursor, int* __restrict__ csr) {
    int e = blockIdx.x * 256 + threadIdx.x;
    if (e < EE) {
        int d = dst[e];
        int p = atomicAdd(&cursor[d], 1);
        csr[p] = src[e];
    }
}

// ---------------- weight transpose + convert: Wt[n][k] = (bf16)W[k][n] ----------------
__global__ __launch_bounds__(256) void k_wt(const float* __restrict__ W1, const float* __restrict__ Wg,
                                            __bf16* __restrict__ W1t, __bf16* __restrict__ Wgt) {
    __shared__ float tile[32][33];
    const float* W = blockIdx.z ? Wg : W1;
    __bf16* Wt = blockIdx.z ? Wgt : W1t;
    int x0 = blockIdx.x * 32;   // n block
    int y0 = blockIdx.y * 32;   // k block
    int tx = threadIdx.x;       // 0..31
    for (int j = threadIdx.y; j < 32; j += 8)
        tile[j][tx] = W[(size_t)(y0 + j) * DD + x0 + tx];
    __syncthreads();
    for (int j = threadIdx.y; j < 32; j += 8)
        Wt[(size_t)(x0 + j) * DD + y0 + tx] = (__bf16)tile[tx][j];
}

// ---------------- weight-stationary bf16 MFMA GEMM (r10 structure, conflict-free slab) ----------------
// Block: 8 waves x 32 cols = 256-col n-slice; 256 rows via 8 m-tiles of 32.
// W slice per wave: 32 cols x 512 K in regs (wf[2][16] = 128 VGPR).
// A-slab LDS: chunk d = kf*128 + r*4 + s (16B chunks), chunk (kf,r,s) holds global
//   k-chunk kf*4 + (s ^ ((r>>1)&3)) of row r  -> 64B row stride + s-XOR = 0-conflict
//   pattern (byte-identical to rounds 3-8's measured-zero reads). Staging writes are
//   lane-linear (conflict-free); source address carries the inverse permutation.
// Stage-early: next m-tile's loads issued at loop top; the __syncthreads drain at
// loop bottom is ~free (issue->barrier distance = full m-tile compute, ~2500cy).
// MODE 1: A fp32 (text), reg-stage + cvt; out = PReLU(BN(A@W1+b1)) bf16
// MODE 2: A bf16 (hg), gload_lds;        out = PReLU(A@Wg + bg)    bf16
template <int MODE>
__global__ __launch_bounds__(512, 2) void k_gemm_w(
    const void* __restrict__ Ap,
    const __bf16* __restrict__ Wt,
    __bf16* __restrict__ Cout,
    const float* __restrict__ bias,
    const float* __restrict__ gamma, const float* __restrict__ beta,
    const float* __restrict__ mean, const float* __restrict__ var,
    const float* __restrict__ alphap)
{
    __shared__ __bf16 slab[2][16384];   // 2 x 32KB

    const int t    = threadIdx.x;
    const int lane = t & 63;
    const int wv   = t >> 6;
    const int l15  = lane & 15;
    const int lhi  = lane >> 4;
    const int work = ((blockIdx.x & 7) << 5) + (blockIdx.x >> 3);  // bijective 256; XCD-affine
    const int nsl  = work & 1;
    const int mb   = work >> 1;
    const int mbase   = mb * 256;
    const int colbase = nsl * 256 + wv * 32;

    // ---- one-time: W fragments into registers ----
    bf16x8 wf[2][16];
#pragma unroll
    for (int C = 0; C < 2; ++C)
#pragma unroll
        for (int kf = 0; kf < 16; ++kf) {
            int col = colbase + C * 16 + l15;
            wf[C][kf] = *(const bf16x8*)(Wt + (size_t)col * DD + kf * 32 + lhi * 8);
        }

    // ---- one-time: per-col epilogue constants ----
    float s0 = 0, s1 = 0, t0 = 0, t1 = 0, al = 0;
    if constexpr (MODE == 1) {
        int c0 = colbase + l15, c1 = c0 + 16;
        float r0 = rsqrtf(var[c0] + 1e-5f), r1 = rsqrtf(var[c1] + 1e-5f);
        s0 = gamma[c0] * r0;  s1 = gamma[c1] * r1;
        t0 = (bias[c0] - mean[c0]) * s0 + beta[c0];
        t1 = (bias[c1] - mean[c1]) * s1 + beta[c1];
        al = alphap[0];
    } else {
        int c0 = colbase + l15, c1 = c0 + 16;
        t0 = bias[c0]; t1 = bias[c1];
        al = alphap[0];
    }

    float4 fa[4][2];   // MODE1 staging regs (4 chunks x 8 fp32)

    auto loadA1 = [&](int mt) {        // MODE1: global fp32 -> regs (chunk d = q*512+t)
        const float* A = (const float*)Ap;
#pragma unroll
        for (int q = 0; q < 4; ++q) {
            int d = q * 512 + t;
            int kf = d >> 7, r = (d >> 2) & 31, s = d & 3;
            int c = kf * 4 + (s ^ ((r >> 1) & 3));
            const float* g = A + (size_t)(mbase + mt * 32 + r) * DD + c * 8;
            fa[q][0] = *(const float4*)g;
            fa[q][1] = *(const float4*)(g + 4);
        }
    };
    auto writeA1 = [&](int bb) {       // cvt + lane-linear ds_write (conflict-free)
#pragma unroll
        for (int q = 0; q < 4; ++q) {
            int d = q * 512 + t;
            bf16x8 o;
            o[0] = (__bf16)fa[q][0].x; o[1] = (__bf16)fa[q][0].y;
            o[2] = (__bf16)fa[q][0].z; o[3] = (__bf16)fa[q][0].w;
            o[4] = (__bf16)fa[q][1].x; o[5] = (__bf16)fa[q][1].y;
            o[6] = (__bf16)fa[q][1].z; o[7] = (__bf16)fa[q][1].w;
            *(bf16x8*)&slab[bb][(size_t)d * 8] = o;
        }
    };
    auto stage2 = [&](int bb, int mt) { // MODE2: gload_lds, perm source, linear dest
        const __bf16* A = (const __bf16*)Ap;
#pragma unroll
        for (int q = 0; q < 4; ++q) {
            int d  = q * 512 + wv * 64 + lane;
            int kf = d >> 7, r = (d >> 2) & 31, s = d & 3;
            int c  = kf * 4 + (s ^ ((r >> 1) & 3));
            const __bf16* g = A + (size_t)(mbase + mt * 32 + r) * DD + c * 8;
            __builtin_amdgcn_global_load_lds(
                (const AS1 unsigned int*)g,
                (AS3 unsigned int*)(&slab[bb][(size_t)(q * 512 + wv * 64) * 8]), 16, 0, 0);
        }
    };

    // ---- prologue: slab 0 ----
    if constexpr (MODE == 1) { loadA1(0); writeA1(0); }
    else                     { stage2(0, 0); }
    __syncthreads();

    // ---- m-loop: 8 tiles of 32 rows ----
#pragma unroll
    for (int mt = 0; mt < 8; ++mt) {
        const int cur = mt & 1, nxt = cur ^ 1;

        // issue next slab's global loads (complete during this tile's compute)
        if (mt < 7) {
            if constexpr (MODE == 1) loadA1(mt + 1);
            else                     stage2(nxt, mt + 1);
        }

        // full-K register compute: 16 kfrags x (2 ds_read + 4 MFMA)
        f32x4 acc[2][2] = {};
        const __bf16* sl = &slab[cur][0];
#pragma unroll
        for (int kf = 0; kf < 16; ++kf) {
            int r0 = l15, r1 = 16 + l15;
            int sA = lhi ^ ((r0 >> 1) & 3);
            int sB = lhi ^ ((r1 >> 1) & 3);
            bf16x8 a0 = *(const bf16x8*)&sl[(kf * 128 + r0 * 4 + sA) * 8];
            bf16x8 a1 = *(const bf16x8*)&sl[(kf * 128 + r1 * 4 + sB) * 8];
            acc[0][0] = __builtin_amdgcn_mfma_f32_16x16x32_bf16(a0, wf[0][kf], acc[0][0], 0, 0, 0);
            acc[0][1] = __builtin_amdgcn_mfma_f32_16x16x32_bf16(a0, wf[1][kf], acc[0][1], 0, 0, 0);
            acc[1][0] = __builtin_amdgcn_mfma_f32_16x16x32_bf16(a1, wf[0][kf], acc[1][0], 0, 0, 0);
            acc[1][1] = __builtin_amdgcn_mfma_f32_16x16x32_bf16(a1, wf[1][kf], acc[1][1], 0, 0, 0);
        }

        // epilogue for this 32x32 wave tile
#pragma unroll
        for (int R = 0; R < 2; ++R)
#pragma unroll
            for (int C = 0; C < 2; ++C) {
                int col  = colbase + C * 16 + l15;
                int rowb = mbase + mt * 32 + R * 16 + (lhi << 2);
                float ss = C ? s1 : s0, tt = C ? t1 : t0;
#pragma unroll
                for (int j = 0; j < 4; ++j) {
                    float x = acc[R][C][j];
                    if constexpr (MODE == 1) x = x * ss + tt;
                    else                     x = x + tt;
                    x = (x >= 0.0f) ? x : al * x;
                    Cout[(size_t)(rowb + j) * DD + col] = (__bf16)x;
                }
            }

        // MODE1: convert+write next slab (fa's vmcnt wait hid under compute)
        if constexpr (MODE == 1) {
            if (mt < 7) writeA1(nxt);
        }

        __syncthreads();   // drain ~free: staging issued a full m-tile ago
    }
}

// ---------------- gather on h (commuted before GEMM2): hg = dinv*(dinv*h + sum dinv[s]*h[s]) ----------------
__global__ __launch_bounds__(256) void k_gather(
    const int* __restrict__ offs, const int* __restrict__ csr,
    const __bf16* __restrict__ h, const float* __restrict__ dinv,
    __bf16* __restrict__ hg)
{
    int blk = blockIdx.x;                              // 0..8191
    int sb  = ((blk & 7) << 10) + (blk >> 3);          // XCD-chunked (bijective)
    int wave = threadIdx.x >> 6;
    int lane = threadIdx.x & 63;
    int node = sb * 4 + wave;
    int c = lane * 8;
    int beg = offs[node], end = offs[node + 1];
    int ne = end - beg;

    float dn = dinv[node];
    bf16x8 sv = *(const bf16x8*)(h + (size_t)node * DD + c);   // self loop
    float a[8];
#pragma unroll
    for (int i = 0; i < 8; ++i) a[i] = dn * (float)sv[i];

    int k = 0;
    for (; k + 4 <= ne; k += 4) {
        int s0 = csr[beg + k + 0];
        int s1 = csr[beg + k + 1];
        int s2 = csr[beg + k + 2];
        int s3 = csr[beg + k + 3];
        float d0 = dinv[s0], d1 = dinv[s1], d2 = dinv[s2], d3 = dinv[s3];
        bf16x8 v0 = *(const bf16x8*)(h + (size_t)s0 * DD + c);
        bf16x8 v1 = *(const bf16x8*)(h + (size_t)s1 * DD + c);
        bf16x8 v2 = *(const bf16x8*)(h + (size_t)s2 * DD + c);
        bf16x8 v3 = *(const bf16x8*)(h + (size_t)s3 * DD + c);
#pragma unroll
        for (int i = 0; i < 8; ++i)
            a[i] += d0 * (float)v0[i] + d1 * (float)v1[i] + d2 * (float)v2[i] + d3 * (float)v3[i];
    }
    for (; k < ne; ++k) {
        int s = csr[beg + k];
        float ds_ = dinv[s];
        bf16x8 v = *(const bf16x8*)(h + (size_t)s * DD + c);
#pragma unroll
        for (int i = 0; i < 8; ++i) a[i] += ds_ * (float)v[i];
    }

    bf16x8 o;
#pragma unroll
    for (int i = 0; i < 8; ++i) o[i] = (__bf16)(dn * a[i]);
    *(bf16x8*)(hg + (size_t)node * DD + c) = o;
}

// ---------------- final: row-L2-norm + residual (pure streaming) ----------------
__global__ __launch_bounds__(256) void k_final(
    const __bf16* __restrict__ g, const float* __restrict__ text, float* __restrict__ out)
{
    int blk = blockIdx.x;                              // 0..8191
    int sb  = ((blk & 7) << 10) + (blk >> 3);          // XCD-chunked
    int wave = threadIdx.x >> 6;
    int lane = threadIdx.x & 63;
    int node = sb * 4 + wave;
    int c = lane * 8;

    bf16x8 gv = *(const bf16x8*)(g + (size_t)node * DD + c);
    float x[8];
    float ss = 0.0f;
#pragma unroll
    for (int i = 0; i < 8; ++i) { x[i] = (float)gv[i]; ss += x[i] * x[i]; }
#pragma unroll
    for (int off = 1; off < 64; off <<= 1) ss += __shfl_xor(ss, off, 64);
    float inv = 1.0f / fmaxf(sqrtf(ss), 1e-12f);

    size_t base = (size_t)node * DD + c;
    float4 t0 = *(const float4*)&text[base];
    float4 t1 = *(const float4*)&text[base + 4];
    float4 o0, o1;
    o0.x = x[0] * inv + t0.x; o0.y = x[1] * inv + t0.y;
    o0.z = x[2] * inv + t0.z; o0.w = x[3] * inv + t0.w;
    o1.x = x[4] * inv + t1.x; o1.y = x[5] * inv + t1.y;
    o1.z = x[6] * inv + t1.z; o1.w = x[7] * inv + t1.w;
    *(float4*)&out[base]     = o0;
    *(float4*)&out[base + 4] = o1;
}

extern "C" void kernel_launch(void* const* d_in, const int* in_sizes, int n_in,
                              void* d_out, int out_size, void* d_ws, size_t ws_size,
                              hipStream_t stream) {
    const float* text   = (const float*)d_in[0];
    const int*   esrc   = (const int*)d_in[1];
    const int*   edst   = (const int*)d_in[2];
    const float* W1     = (const float*)d_in[3];
    const float* b1     = (const float*)d_in[4];
    const float* gamma  = (const float*)d_in[5];
    const float* beta   = (const float*)d_in[6];
    const float* rmean  = (const float*)d_in[7];
    const float* rvar   = (const float*)d_in[8];
    const float* alpha1 = (const float*)d_in[9];
    const float* Wg     = (const float*)d_in[10];
    const float* bg     = (const float*)d_in[11];
    const float* alpha2 = (const float*)d_in[12];
    float* out = (float*)d_out;

    // workspace layout (~66.5 MiB)
    char* p = (char*)d_ws;
    auto alloc = [&](size_t bytes) { char* r = p; p += (bytes + 255) & ~(size_t)255; return r; };
    int*    cnt     = (int*)alloc((size_t)NN * 4);
    int*    offs    = (int*)alloc((size_t)(NN + 1) * 4);
    int*    cursor  = (int*)alloc((size_t)NN * 4);
    float*  dinv    = (float*)alloc((size_t)NN * 4);
    int*    csr     = (int*)alloc((size_t)EE * 4);
    __bf16* W1t     = (__bf16*)alloc((size_t)DD * DD * 2);
    __bf16* Wgt     = (__bf16*)alloc((size_t)DD * DD * 2);
    __bf16* h_bf    = (__bf16*)alloc((size_t)NN * DD * 2);
    __bf16* hg      = (__bf16*)alloc((size_t)NN * DD * 2);
    __bf16* g       = h_bf;   // alias: h dead after gather, g written by GEMM2

    // 1) CSR build + dinv
    k_zero<<<NN / 256, 256, 0, stream>>>(cnt);
    k_count<<<EE / 256, 256, 0, stream>>>(edst, cnt);
    k_scan<<<1, 1024, 0, stream>>>(cnt, offs, cursor, dinv);
    k_fill<<<EE / 256, 256, 0, stream>>>(esrc, edst, cursor, csr);

    // 2) weights -> bf16 [n][k]
    k_wt<<<dim3(16, 16, 2), dim3(32, 8), 0, stream>>>(W1, Wg, W1t, Wgt);

    // 3) h = PReLU(BN(text@W1 + b1))   [weight-stationary, fp32 A inline-cvt]
    k_gemm_w<1><<<256, 512, 0, stream>>>(text, W1t, h_bf, b1, gamma, beta, rmean, rvar, alpha1);

    // 4) hg = dinv*(A+I)*dinv * h      [gather commuted before GEMM2]
    k_gather<<<NN / 4, 256, 0, stream>>>(offs, csr, h_bf, dinv, hg);

    // 5) g = PReLU(hg@Wg + bg)         [weight-stationary]
    k_gemm_w<2><<<256, 512, 0, stream>>>(hg, Wgt, g, bg, nullptr, nullptr, nullptr, nullptr, alpha2);

    // 6) out = g/||g|| + text
    k_final<<<NN / 4, 256, 0, stream>>>(g, text, out);
}